// Round 19
// baseline (437.749 us; speedup 1.0000x reference)
//
#include <hip/hip_runtime.h>
#include <hip/hip_fp16.h>
#include <cstddef>

#define DIM 2048
#define NTOK 8192
#define NEUMANN_ITERS 6

// Math (validated rounds 1-18):
//   omega = P Q^T, P=[U|V], Q=[sV|-sU], G = Q^T P  (16x16)
//   Y = (I - G/2)^{-1}(I + G/2)  via Neumann-Horner: Y <- B + 0.5*G*Y, B=I+G/2
//   out = x + sum_k c[k] P[:,k],
//   c[k] = 0.5*s* sum_j Z[k][j] b[j],  Z = I + Y,
//     b[j<8] = av[j], b[j>=8] = -au[j-8];  au = x.U, av = x.V
//
// Structural lessons baked in:
//  - No 1-block dispatches (r2/4). No redundant per-block gram (r5).
//    No min-waves launch_bounds clause (r6: spill).
//  - Config space exhausted at ~40-47us fused: r11 (16w x 2r) 41, r16
//    (32w x 1r) ~40 champion, r18 (1 blk/CU) 46. Latency-bound, not pipe.
//  - x-in-regs at 2 rows/wave SPILLS (r13/r17: 64+ x regs + 32 acc > 128).
//    THIS round: x-in-regs at 1 ROW/wave as f16 pairs = only 16 VGPR
//    (fdot2 consumes h2 anyway). Budget ~60 <= 64 keeps 32 waves/CU.
//    Phase 2 reads ZERO globals (out = f32(xh) + corr; r13 validated
//    absmax 0.031 << 0.108). All 16 x loads issue at kernel top -> one
//    latency exposure/wave.
//  - f16-pair LDS UV + fdot2 + DPP butterfly + hfma2 (r11/r16 champion
//    path; r15 fp8 decode doubled VALU).
//  - LDS reads uint4 @16B lane stride (r12: 32B stride = 2.16M conflicts).
//  - cvt_pkrtz returns __fp16 ext_vector(2): bit_cast everywhere.
//  - FULL unroll on xh-indexed loops (rule #20: runtime reg idx = scratch).

typedef _Float16 h2 __attribute__((ext_vector_type(2)));

__device__ __forceinline__ unsigned pkh(float lo, float hi) {
  auto p = __builtin_amdgcn_cvt_pkrtz(lo, hi);   // v_cvt_pkrtz_f16_f32
  return __builtin_bit_cast(unsigned, p);
}
__device__ __forceinline__ h2 cvt2h(float lo, float hi) {
  auto p = __builtin_amdgcn_cvt_pkrtz(lo, hi);
  return __builtin_bit_cast(h2, p);
}

template <int CTRL>
__device__ __forceinline__ float dpp_add(float v) {
  const int t =
      __builtin_amdgcn_update_dpp(0, __float_as_int(v), CTRL, 0xf, 0xf, true);
  return v + __int_as_float(t);
}
__device__ __forceinline__ float wave_red(float v) {
  v = dpp_add<0xB1>(v);    // quad_perm [1,0,3,2]  (xor 1)
  v = dpp_add<0x4E>(v);    // quad_perm [2,3,0,1]  (xor 2)
  v = dpp_add<0x141>(v);   // row_half_mirror      (pairs halves of 8)
  v = dpp_add<0x140>(v);   // row_mirror           (pairs halves of 16)
  v += __shfl_xor(v, 16, 64);
  v += __shfl_xor(v, 32, 64);
  return v;
}

// ---------------------------------------------------------------------------
// 1) Gram: one block per entry e=(q,i,j); 256 threads reduce over d=2048.
// ---------------------------------------------------------------------------
__global__ __launch_bounds__(256) void rora_gram(
    const float* __restrict__ U, const float* __restrict__ V,
    float* __restrict__ prod) {
  const int e = blockIdx.x;            // 0..191
  const int q = e >> 6;                // 0: U^T U, 1: U^T V, 2: V^T V
  const int i = (e >> 3) & 7, j = e & 7;
  const float* A = (q == 2) ? V : U;
  const float* B = (q == 0) ? U : V;
  const int t = threadIdx.x;
  float acc = 0.f;
#pragma unroll
  for (int s = 0; s < 8; ++s) {
    const int d = s * 256 + t;
    acc = fmaf(A[d * 8 + i], B[d * 8 + j], acc);
  }
#pragma unroll
  for (int m = 1; m < 64; m <<= 1) acc += __shfl_xor(acc, m, 64);
  __shared__ float wsum[4];
  if ((t & 63) == 0) wsum[t >> 6] = acc;
  __syncthreads();
  if (t == 0) prod[e] = (wsum[0] + wsum[1]) + (wsum[2] + wsum[3]);
}

// ---------------------------------------------------------------------------
// 2) Fused: UV->LDS f16-pair staging + 16x16 setup + streaming main.
//    1024 threads = 16 waves x 1 row; grid 512; 2 blocks/CU = 32 waves/CU.
//    uvQ[q][P].comp(m) = half2( W[2P][4q+m], W[2P+1][4q+m] ),
//      slots: q=0 U cols 0-3, q=1 U cols 4-7, q=2 V cols 0-3, q=3 V cols 4-7.
// ---------------------------------------------------------------------------
__global__ __launch_bounds__(1024) void rora_fused(
    const float* __restrict__ x, const float* __restrict__ U,
    const float* __restrict__ V, const float* __restrict__ gate,
    const float* __restrict__ prod, float* __restrict__ out) {
  __shared__ uint4 uvQ[4][DIM / 2];   // 64 KB
  __shared__ float prodS[192];        // [q*64 + i*8 + j]
  __shared__ float Gs[16][17];
  __shared__ float Bm[16][17];
  __shared__ float Ya[16][17];
  __shared__ float Yb[16][17];
  const int t = threadIdx.x;
  const int wv = t >> 6, lane = t & 63;
  const int row = blockIdx.x * 16 + wv;
  const float2* x2 = (const float2*)(x + (size_t)row * DIM);

  // ---- x row -> registers as f16 pairs (16 VGPR); issued FIRST so the
  //      HBM latency hides under the whole staging+Neumann preamble ----
  h2 xh[16];
#pragma unroll
  for (int i = 0; i < 16; ++i) {
    const float2 xp = x2[i * 64 + lane];
    xh[i] = cvt2h(xp.x, xp.y);
  }

  // ---- stage U,V -> LDS as f16 d-pairs; thread t owns pair P=t ----
  {
    const float4* U4 = (const float4*)U;
    const float4* V4 = (const float4*)V;
    const int P = t;                  // d-pair (2P, 2P+1)
    const float4 a0 = U4[4 * P + 0], a1 = U4[4 * P + 1];  // U[2P][0..7]
    const float4 a2 = U4[4 * P + 2], a3 = U4[4 * P + 3];  // U[2P+1][0..7]
    const float4 b0 = V4[4 * P + 0], b1 = V4[4 * P + 1];
    const float4 b2 = V4[4 * P + 2], b3 = V4[4 * P + 3];
    uvQ[0][P] = make_uint4(pkh(a0.x, a2.x), pkh(a0.y, a2.y),
                           pkh(a0.z, a2.z), pkh(a0.w, a2.w));
    uvQ[1][P] = make_uint4(pkh(a1.x, a3.x), pkh(a1.y, a3.y),
                           pkh(a1.z, a3.z), pkh(a1.w, a3.w));
    uvQ[2][P] = make_uint4(pkh(b0.x, b2.x), pkh(b0.y, b2.y),
                           pkh(b0.z, b2.z), pkh(b0.w, b2.w));
    uvQ[3][P] = make_uint4(pkh(b1.x, b3.x), pkh(b1.y, b3.y),
                           pkh(b1.z, b3.z), pkh(b1.w, b3.w));
  }

  // ---- 16x16 setup (f32, from ws gram products) ----
  if (t < 192) prodS[t] = prod[t];
  __syncthreads();
  const float sg = 1.f / (1.f + expf(-gate[0]));
  if (t < 256) {
    const int r = t >> 4, c = t & 15;
    float g;
    if (r < 8) g = (c < 8) ? sg * prodS[64 + c * 8 + r]              // (V^T U)
                           : sg * prodS[128 + r * 8 + (c - 8)];      // (V^T V)
    else       g = (c < 8) ? -sg * prodS[(r - 8) * 8 + c]            // -(U^T U)
                           : -sg * prodS[64 + (r - 8) * 8 + (c - 8)];
    const float b = ((r == c) ? 1.f : 0.f) + 0.5f * g;
    Gs[r][c] = g;
    Bm[r][c] = b;
    Ya[r][c] = b;
  }
  __syncthreads();
#pragma unroll
  for (int m = 0; m < NEUMANN_ITERS; ++m) {   // ends in Ya (last m odd)
    if (t < 256) {
      const int r = t >> 4, c = t & 15;
      const float (*Yp)[17] = (m & 1) ? Yb : Ya;
      float (*Yn)[17] = (m & 1) ? Ya : Yb;
      float acc = Bm[r][c];
#pragma unroll
      for (int j = 0; j < 16; ++j)
        acc = fmaf(0.5f * Gs[r][j], Yp[j][c], acc);
      Yn[r][c] = acc;
    }
    __syncthreads();   // final barrier also orders uvQ staging before reads
  }

  // ---- phase 1: a = [x.U | x.V]; lane owns d-pairs P = i*64+lane ----
  float a[16];
#pragma unroll
  for (int k = 0; k < 16; ++k) a[k] = 0.f;

#pragma unroll
  for (int i = 0; i < 16; ++i) {
    const int P = i * 64 + lane;
    const uint4 qa = uvQ[0][P], qb = uvQ[1][P];
    const uint4 qc = uvQ[2][P], qd = uvQ[3][P];
#if __has_builtin(__builtin_amdgcn_fdot2)
#define D2(acc, w) \
  acc = __builtin_amdgcn_fdot2(xh[i], __builtin_bit_cast(h2, w), acc, false)
    D2(a[0], qa.x);  D2(a[1], qa.y);  D2(a[2], qa.z);  D2(a[3], qa.w);
    D2(a[4], qb.x);  D2(a[5], qb.y);  D2(a[6], qb.z);  D2(a[7], qb.w);
    D2(a[8], qc.x);  D2(a[9], qc.y);  D2(a[10], qc.z); D2(a[11], qc.w);
    D2(a[12], qd.x); D2(a[13], qd.y); D2(a[14], qd.z); D2(a[15], qd.w);
#undef D2
#else
    const float x0 = (float)(xh[i])[0], x1 = (float)(xh[i])[1];
    const __half2 uu[16] = {
        __builtin_bit_cast(__half2, qa.x), __builtin_bit_cast(__half2, qa.y),
        __builtin_bit_cast(__half2, qa.z), __builtin_bit_cast(__half2, qa.w),
        __builtin_bit_cast(__half2, qb.x), __builtin_bit_cast(__half2, qb.y),
        __builtin_bit_cast(__half2, qb.z), __builtin_bit_cast(__half2, qb.w),
        __builtin_bit_cast(__half2, qc.x), __builtin_bit_cast(__half2, qc.y),
        __builtin_bit_cast(__half2, qc.z), __builtin_bit_cast(__half2, qc.w),
        __builtin_bit_cast(__half2, qd.x), __builtin_bit_cast(__half2, qd.y),
        __builtin_bit_cast(__half2, qd.z), __builtin_bit_cast(__half2, qd.w)};
#pragma unroll
    for (int k = 0; k < 16; ++k)
      a[k] = fmaf(x0, __low2float(uu[k]), fmaf(x1, __high2float(uu[k]), a[k]));
#endif
  }

  // butterfly: 4 DPP VALU levels + 2 shuffles per value
#pragma unroll
  for (int k = 0; k < 16; ++k) a[k] = wave_red(a[k]);

  // c[k] = 0.5*s * sum_j Z[k][j] b[j]; lane kk=lane&15 computes row kk.
  __half2 ch[16];
  {
    const int kk = lane & 15;
    float zrow[16];
#pragma unroll
    for (int j = 0; j < 16; ++j)
      zrow[j] = Ya[kk][j] + ((j == kk) ? 1.f : 0.f);
    const float hs = 0.5f * sg;
    float s = 0.f;
#pragma unroll
    for (int j = 0; j < 8; ++j) {
      s = fmaf(zrow[j], a[8 + j], s);     //  Z[k][j]   * av[j]
      s = fmaf(-zrow[8 + j], a[j], s);    // -Z[k][8+j] * au[j]
    }
    const float cp = hs * s;
#pragma unroll
    for (int k = 0; k < 16; ++k) ch[k] = __float2half2_rn(__shfl(cp, k, 64));
  }

  // ---- phase 2: out = f32(xh) + corr; ZERO global reads ----
  float2* o2 = (float2*)(out + (size_t)row * DIM);
  const __half2 hz = __float2half2_rn(0.f);
#define HF(acc, c, w) acc = __hfma2(c, __builtin_bit_cast(__half2, w), acc)
#pragma unroll
  for (int i = 0; i < 16; ++i) {
    const int P = i * 64 + lane;
    const uint4 qa = uvQ[0][P], qb = uvQ[1][P];
    const uint4 qc = uvQ[2][P], qd = uvQ[3][P];
    __half2 t0 = hz, t1 = hz;
    HF(t0, ch[0], qa.x);  HF(t0, ch[1], qa.y);
    HF(t0, ch[2], qa.z);  HF(t0, ch[3], qa.w);
    HF(t0, ch[4], qb.x);  HF(t0, ch[5], qb.y);
    HF(t0, ch[6], qb.z);  HF(t0, ch[7], qb.w);
    HF(t1, ch[8], qc.x);  HF(t1, ch[9], qc.y);
    HF(t1, ch[10], qc.z); HF(t1, ch[11], qc.w);
    HF(t1, ch[12], qd.x); HF(t1, ch[13], qd.y);
    HF(t1, ch[14], qd.z); HF(t1, ch[15], qd.w);
    const __half2 s = __hadd2(t0, t1);
    o2[P] = make_float2((float)(xh[i])[0] + __low2float(s),
                        (float)(xh[i])[1] + __high2float(s));
  }
#undef HF
}

extern "C" void kernel_launch(void* const* d_in, const int* in_sizes, int n_in,
                              void* d_out, int out_size, void* d_ws, size_t ws_size,
                              hipStream_t stream) {
  const float* x    = (const float*)d_in[0];
  const float* U    = (const float*)d_in[1];
  const float* V    = (const float*)d_in[2];
  const float* gate = (const float*)d_in[3];
  float* out = (float*)d_out;
  float* prodw = (float*)d_ws;   // 192 floats

  rora_gram<<<192, 256, 0, stream>>>(U, V, prodw);
  rora_fused<<<NTOK / 16, 1024, 0, stream>>>(x, U, V, gate, prodw, out);
}

// Round 20
// 49.118 us; speedup vs baseline: 8.9122x; 8.9122x over previous
//
#include <hip/hip_runtime.h>
#include <hip/hip_fp16.h>
#include <cstddef>

#define DIM 2048
#define NTOK 8192
#define NEUMANN_ITERS 6

// Math (validated rounds 1-19):
//   omega = P Q^T, P=[U|V], Q=[sV|-sU], G = Q^T P  (16x16)
//   Y = (I - G/2)^{-1}(I + G/2)  via Neumann-Horner: Y <- B + 0.5*G*Y, B=I+G/2
//   out = x + sum_k c[k] P[:,k],
//   c[k] = 0.5*s* sum_j Z[k][j] b[j],  Z = I + Y,
//     b[j<8] = av[j], b[j>=8] = -au[j-8];  au = x.U, av = x.V
//
// Structural lessons baked in:
//  - No 1-block dispatches (r2/4). No redundant per-block gram (r5).
//    No min-waves launch_bounds clause (r6: spill).
//  - VGPR caps BY BLOCK SIZE: 1024-thr -> 64 (r19: xh+a+ch ~90 -> 938MB
//    scratch spill, 437us); 512-thr -> 128. x-in-regs NEVER fits with
//    accumulators; x is re-read from global in phase 2 (L3-absorbed).
//  - f16-pair LDS UV + fdot2 + DPP butterfly + hfma2 (champion datapath;
//    r15 fp8 decode doubled VALU).
//  - uvE/uvO quad layout (r13-validated): float4 x I/O with ALL
//    ds_read_b128 at 16B lane stride (r12's float4 had 32B stride =
//    2.16M conflicts; this fixes it).
//  - 512 thr = 8 waves x 2 rows = 16 rows/block, grid 512, ~70KB LDS ->
//    2 blocks/CU = 16 waves/CU; LDS sweep ~10us/CU (shared reads serve
//    2 rows); float4 = 16B/lane coalescing sweet spot (m13's 6.3TB/s).
//  - cvt_pkrtz returns __fp16 ext_vector(2): bit_cast everywhere.
//  - No runtime indexing of register arrays (full unroll).

typedef _Float16 h2 __attribute__((ext_vector_type(2)));

__device__ __forceinline__ unsigned pkh(float lo, float hi) {
  auto p = __builtin_amdgcn_cvt_pkrtz(lo, hi);   // v_cvt_pkrtz_f16_f32
  return __builtin_bit_cast(unsigned, p);
}
__device__ __forceinline__ h2 cvt2h(float lo, float hi) {
  auto p = __builtin_amdgcn_cvt_pkrtz(lo, hi);
  return __builtin_bit_cast(h2, p);
}

template <int CTRL>
__device__ __forceinline__ float dpp_add(float v) {
  const int t =
      __builtin_amdgcn_update_dpp(0, __float_as_int(v), CTRL, 0xf, 0xf, true);
  return v + __int_as_float(t);
}
__device__ __forceinline__ float wave_red(float v) {
  v = dpp_add<0xB1>(v);    // quad_perm [1,0,3,2]  (xor 1)
  v = dpp_add<0x4E>(v);    // quad_perm [2,3,0,1]  (xor 2)
  v = dpp_add<0x141>(v);   // row_half_mirror      (pairs halves of 8)
  v = dpp_add<0x140>(v);   // row_mirror           (pairs halves of 16)
  v += __shfl_xor(v, 16, 64);
  v += __shfl_xor(v, 32, 64);
  return v;
}

// ---------------------------------------------------------------------------
// 1) Gram: one block per entry e=(q,i,j); 256 threads reduce over d=2048.
// ---------------------------------------------------------------------------
__global__ __launch_bounds__(256) void rora_gram(
    const float* __restrict__ U, const float* __restrict__ V,
    float* __restrict__ prod) {
  const int e = blockIdx.x;            // 0..191
  const int q = e >> 6;                // 0: U^T U, 1: U^T V, 2: V^T V
  const int i = (e >> 3) & 7, j = e & 7;
  const float* A = (q == 2) ? V : U;
  const float* B = (q == 0) ? U : V;
  const int t = threadIdx.x;
  float acc = 0.f;
#pragma unroll
  for (int s = 0; s < 8; ++s) {
    const int d = s * 256 + t;
    acc = fmaf(A[d * 8 + i], B[d * 8 + j], acc);
  }
#pragma unroll
  for (int m = 1; m < 64; m <<= 1) acc += __shfl_xor(acc, m, 64);
  __shared__ float wsum[4];
  if ((t & 63) == 0) wsum[t >> 6] = acc;
  __syncthreads();
  if (t == 0) prod[e] = (wsum[0] + wsum[1]) + (wsum[2] + wsum[3]);
}

// ---------------------------------------------------------------------------
// 2) Fused. LDS layout (quad m covers d = 4m..4m+3):
//    uvE[q][m].comp(c) = half2( W[4m  ][4q+c], W[4m+1][4q+c] )
//    uvO[q][m].comp(c) = half2( W[4m+2][4q+c], W[4m+3][4q+c] )
//    q=0: U cols 0-3, q=1: U 4-7, q=2: V 0-3, q=3: V 4-7.
//    512 thr = 8 waves x 2 rows; grid 512; 2 blocks/CU = 16 waves/CU.
// ---------------------------------------------------------------------------
__global__ __launch_bounds__(512) void rora_fused(
    const float* __restrict__ x, const float* __restrict__ U,
    const float* __restrict__ V, const float* __restrict__ gate,
    const float* __restrict__ prod, float* __restrict__ out) {
  __shared__ uint4 uvE[4][DIM / 4];   // 32 KB
  __shared__ uint4 uvO[4][DIM / 4];   // 32 KB
  __shared__ float prodS[192];        // [q*64 + i*8 + j]
  __shared__ float Gs[16][17];
  __shared__ float Bm[16][17];
  __shared__ float Ya[16][17];
  __shared__ float Yb[16][17];
  const int t = threadIdx.x;

  // ---- stage U,V -> LDS; thread t owns quad Q=t (d = 4t..4t+3) ----
  {
    const float4* U4 = (const float4*)U;
    const float4* V4 = (const float4*)V;
    const int Q = t;
    const float4 u0 = U4[8 * Q + 0], u1 = U4[8 * Q + 1];
    const float4 u2 = U4[8 * Q + 2], u3 = U4[8 * Q + 3];
    const float4 u4 = U4[8 * Q + 4], u5 = U4[8 * Q + 5];
    const float4 u6 = U4[8 * Q + 6], u7 = U4[8 * Q + 7];
    const float4 v0 = V4[8 * Q + 0], v1 = V4[8 * Q + 1];
    const float4 v2 = V4[8 * Q + 2], v3 = V4[8 * Q + 3];
    const float4 v4 = V4[8 * Q + 4], v5 = V4[8 * Q + 5];
    const float4 v6 = V4[8 * Q + 6], v7 = V4[8 * Q + 7];
    uvE[0][Q] = make_uint4(pkh(u0.x, u2.x), pkh(u0.y, u2.y),
                           pkh(u0.z, u2.z), pkh(u0.w, u2.w));
    uvE[1][Q] = make_uint4(pkh(u1.x, u3.x), pkh(u1.y, u3.y),
                           pkh(u1.z, u3.z), pkh(u1.w, u3.w));
    uvO[0][Q] = make_uint4(pkh(u4.x, u6.x), pkh(u4.y, u6.y),
                           pkh(u4.z, u6.z), pkh(u4.w, u6.w));
    uvO[1][Q] = make_uint4(pkh(u5.x, u7.x), pkh(u5.y, u7.y),
                           pkh(u5.z, u7.z), pkh(u5.w, u7.w));
    uvE[2][Q] = make_uint4(pkh(v0.x, v2.x), pkh(v0.y, v2.y),
                           pkh(v0.z, v2.z), pkh(v0.w, v2.w));
    uvE[3][Q] = make_uint4(pkh(v1.x, v3.x), pkh(v1.y, v3.y),
                           pkh(v1.z, v3.z), pkh(v1.w, v3.w));
    uvO[2][Q] = make_uint4(pkh(v4.x, v6.x), pkh(v4.y, v6.y),
                           pkh(v4.z, v6.z), pkh(v4.w, v6.w));
    uvO[3][Q] = make_uint4(pkh(v5.x, v7.x), pkh(v5.y, v7.y),
                           pkh(v5.z, v7.z), pkh(v5.w, v7.w));
  }

  // ---- 16x16 setup (f32, from ws gram products) ----
  if (t < 192) prodS[t] = prod[t];
  __syncthreads();
  const float sg = 1.f / (1.f + expf(-gate[0]));
  if (t < 256) {
    const int r = t >> 4, c = t & 15;
    float g;
    if (r < 8) g = (c < 8) ? sg * prodS[64 + c * 8 + r]              // (V^T U)
                           : sg * prodS[128 + r * 8 + (c - 8)];      // (V^T V)
    else       g = (c < 8) ? -sg * prodS[(r - 8) * 8 + c]            // -(U^T U)
                           : -sg * prodS[64 + (r - 8) * 8 + (c - 8)];
    const float b = ((r == c) ? 1.f : 0.f) + 0.5f * g;
    Gs[r][c] = g;
    Bm[r][c] = b;
    Ya[r][c] = b;
  }
  __syncthreads();
#pragma unroll
  for (int m = 0; m < NEUMANN_ITERS; ++m) {   // ends in Ya (last m odd)
    if (t < 256) {
      const int r = t >> 4, c = t & 15;
      const float (*Yp)[17] = (m & 1) ? Yb : Ya;
      float (*Yn)[17] = (m & 1) ? Ya : Yb;
      float acc = Bm[r][c];
#pragma unroll
      for (int j = 0; j < 16; ++j)
        acc = fmaf(0.5f * Gs[r][j], Yp[j][c], acc);
      Yn[r][c] = acc;
    }
    __syncthreads();   // final barrier also orders uvE/uvO staging
  }

  // ---- main: 8 waves, 2 rows/wave; lane owns quads m = i*64+lane ----
  const int wv = t >> 6, lane = t & 63;
  const int row0 = blockIdx.x * 16 + wv * 2;
  const float4* x4A = (const float4*)(x + (size_t)row0 * DIM);
  const float4* x4B = x4A + DIM / 4;

  float a0[16], a1[16];
#pragma unroll
  for (int k = 0; k < 16; ++k) { a0[k] = 0.f; a1[k] = 0.f; }

#if __has_builtin(__builtin_amdgcn_fdot2)
#define D2(acc, xp, w) \
  acc = __builtin_amdgcn_fdot2(xp, __builtin_bit_cast(h2, w), acc, false)
#else
#define D2(acc, xp, w)                                                  \
  {                                                                     \
    const __half2 _u = __builtin_bit_cast(__half2, w);                  \
    acc = fmaf((float)(xp)[0], __low2float(_u),                         \
               fmaf((float)(xp)[1], __high2float(_u), acc));            \
  }
#endif
#define KQ(arr, base, W, xp)      \
  D2(arr[base + 0], xp, W.x);     \
  D2(arr[base + 1], xp, W.y);     \
  D2(arr[base + 2], xp, W.z);     \
  D2(arr[base + 3], xp, W.w);

  // phase 1: a = [x.U | x.V]; float4 x loads, LDS reads @16B lane stride
#pragma unroll 2
  for (int i = 0; i < 8; ++i) {
    const int m = i * 64 + lane;
    const float4 xA = x4A[m], xB = x4B[m];
    const h2 xa0 = cvt2h(xA.x, xA.y), xa1 = cvt2h(xA.z, xA.w);
    const h2 xb0 = cvt2h(xB.x, xB.y), xb1 = cvt2h(xB.z, xB.w);
    const uint4 E0 = uvE[0][m], E1 = uvE[1][m];
    const uint4 E2 = uvE[2][m], E3 = uvE[3][m];
    const uint4 O0 = uvO[0][m], O1 = uvO[1][m];
    const uint4 O2 = uvO[2][m], O3 = uvO[3][m];
    KQ(a0, 0, E0, xa0);  KQ(a0, 4, E1, xa0);
    KQ(a0, 8, E2, xa0);  KQ(a0, 12, E3, xa0);
    KQ(a0, 0, O0, xa1);  KQ(a0, 4, O1, xa1);
    KQ(a0, 8, O2, xa1);  KQ(a0, 12, O3, xa1);
    KQ(a1, 0, E0, xb0);  KQ(a1, 4, E1, xb0);
    KQ(a1, 8, E2, xb0);  KQ(a1, 12, E3, xb0);
    KQ(a1, 0, O0, xb1);  KQ(a1, 4, O1, xb1);
    KQ(a1, 8, O2, xb1);  KQ(a1, 12, O3, xb1);
  }
#undef KQ
#undef D2

  // butterfly: 4 DPP VALU levels + 2 shuffles per value
#pragma unroll
  for (int k = 0; k < 16; ++k) {
    a0[k] = wave_red(a0[k]);
    a1[k] = wave_red(a1[k]);
  }

  // c[k] = 0.5*s * sum_j Z[k][j] b[j]; lane kk=lane&15 computes row kk.
  __half2 ch0[16], ch1[16];
  {
    const int kk = lane & 15;
    float zrow[16];
#pragma unroll
    for (int j = 0; j < 16; ++j)
      zrow[j] = Ya[kk][j] + ((j == kk) ? 1.f : 0.f);
    const float hs = 0.5f * sg;
    float s0 = 0.f, s1 = 0.f;
#pragma unroll
    for (int j = 0; j < 8; ++j) {
      s0 = fmaf(zrow[j], a0[8 + j], s0);     //  Z[k][j]   * av[j]
      s0 = fmaf(-zrow[8 + j], a0[j], s0);    // -Z[k][8+j] * au[j]
      s1 = fmaf(zrow[j], a1[8 + j], s1);
      s1 = fmaf(-zrow[8 + j], a1[j], s1);
    }
    const float cp0 = hs * s0, cp1 = hs * s1;
#pragma unroll
    for (int k = 0; k < 16; ++k) {
      ch0[k] = __float2half2_rn(__shfl(cp0, k, 64));
      ch1[k] = __float2half2_rn(__shfl(cp1, k, 64));
    }
  }

  // phase 2: out = x + corr; x re-read (L3-hot), float4 I/O
  float4* o4A = (float4*)(out + (size_t)row0 * DIM);
  float4* o4B = o4A + DIM / 4;
  const __half2 hz = __float2half2_rn(0.f);
#define HF2(acc, c, w) acc = __hfma2(c, __builtin_bit_cast(__half2, w), acc)
#pragma unroll 2
  for (int i = 0; i < 8; ++i) {
    const int m = i * 64 + lane;
    const float4 xA = x4A[m], xB = x4B[m];
    const uint4 E0 = uvE[0][m], E1 = uvE[1][m];
    const uint4 E2 = uvE[2][m], E3 = uvE[3][m];
    const uint4 O0 = uvO[0][m], O1 = uvO[1][m];
    const uint4 O2 = uvO[2][m], O3 = uvO[3][m];
    // row A
    __half2 eA0 = hz, eA1 = hz, oA0 = hz, oA1 = hz;
    HF2(eA0, ch0[0], E0.x);  HF2(eA0, ch0[1], E0.y);
    HF2(eA0, ch0[2], E0.z);  HF2(eA0, ch0[3], E0.w);
    HF2(eA0, ch0[4], E1.x);  HF2(eA0, ch0[5], E1.y);
    HF2(eA0, ch0[6], E1.z);  HF2(eA0, ch0[7], E1.w);
    HF2(eA1, ch0[8], E2.x);  HF2(eA1, ch0[9], E2.y);
    HF2(eA1, ch0[10], E2.z); HF2(eA1, ch0[11], E2.w);
    HF2(eA1, ch0[12], E3.x); HF2(eA1, ch0[13], E3.y);
    HF2(eA1, ch0[14], E3.z); HF2(eA1, ch0[15], E3.w);
    HF2(oA0, ch0[0], O0.x);  HF2(oA0, ch0[1], O0.y);
    HF2(oA0, ch0[2], O0.z);  HF2(oA0, ch0[3], O0.w);
    HF2(oA0, ch0[4], O1.x);  HF2(oA0, ch0[5], O1.y);
    HF2(oA0, ch0[6], O1.z);  HF2(oA0, ch0[7], O1.w);
    HF2(oA1, ch0[8], O2.x);  HF2(oA1, ch0[9], O2.y);
    HF2(oA1, ch0[10], O2.z); HF2(oA1, ch0[11], O2.w);
    HF2(oA1, ch0[12], O3.x); HF2(oA1, ch0[13], O3.y);
    HF2(oA1, ch0[14], O3.z); HF2(oA1, ch0[15], O3.w);
    const __half2 sEA = __hadd2(eA0, eA1);
    const __half2 sOA = __hadd2(oA0, oA1);
    float4 oA;
    oA.x = xA.x + __low2float(sEA);
    oA.y = xA.y + __high2float(sEA);
    oA.z = xA.z + __low2float(sOA);
    oA.w = xA.w + __high2float(sOA);
    o4A[m] = oA;
    // row B
    __half2 eB0 = hz, eB1 = hz, oB0 = hz, oB1 = hz;
    HF2(eB0, ch1[0], E0.x);  HF2(eB0, ch1[1], E0.y);
    HF2(eB0, ch1[2], E0.z);  HF2(eB0, ch1[3], E0.w);
    HF2(eB0, ch1[4], E1.x);  HF2(eB0, ch1[5], E1.y);
    HF2(eB0, ch1[6], E1.z);  HF2(eB0, ch1[7], E1.w);
    HF2(eB1, ch1[8], E2.x);  HF2(eB1, ch1[9], E2.y);
    HF2(eB1, ch1[10], E2.z); HF2(eB1, ch1[11], E2.w);
    HF2(eB1, ch1[12], E3.x); HF2(eB1, ch1[13], E3.y);
    HF2(eB1, ch1[14], E3.z); HF2(eB1, ch1[15], E3.w);
    HF2(oB0, ch1[0], O0.x);  HF2(oB0, ch1[1], O0.y);
    HF2(oB0, ch1[2], O0.z);  HF2(oB0, ch1[3], O0.w);
    HF2(oB0, ch1[4], O1.x);  HF2(oB0, ch1[5], O1.y);
    HF2(oB0, ch1[6], O1.z);  HF2(oB0, ch1[7], O1.w);
    HF2(oB1, ch1[8], O2.x);  HF2(oB1, ch1[9], O2.y);
    HF2(oB1, ch1[10], O2.z); HF2(oB1, ch1[11], O2.w);
    HF2(oB1, ch1[12], O3.x); HF2(oB1, ch1[13], O3.y);
    HF2(oB1, ch1[14], O3.z); HF2(oB1, ch1[15], O3.w);
    const __half2 sEB = __hadd2(eB0, eB1);
    const __half2 sOB = __hadd2(oB0, oB1);
    float4 oB;
    oB.x = xB.x + __low2float(sEB);
    oB.y = xB.y + __high2float(sEB);
    oB.z = xB.z + __low2float(sOB);
    oB.w = xB.w + __high2float(sOB);
    o4B[m] = oB;
  }
#undef HF2
}

extern "C" void kernel_launch(void* const* d_in, const int* in_sizes, int n_in,
                              void* d_out, int out_size, void* d_ws, size_t ws_size,
                              hipStream_t stream) {
  const float* x    = (const float*)d_in[0];
  const float* U    = (const float*)d_in[1];
  const float* V    = (const float*)d_in[2];
  const float* gate = (const float*)d_in[3];
  float* out = (float*)d_out;
  float* prodw = (float*)d_ws;   // 192 floats

  rora_gram<<<192, 256, 0, stream>>>(U, V, prodw);
  rora_fused<<<NTOK / 16, 512, 0, stream>>>(x, U, V, gate, prodw, out);
}

// Round 21
// 46.474 us; speedup vs baseline: 9.4193x; 1.0569x over previous
//
#include <hip/hip_runtime.h>
#include <hip/hip_fp16.h>
#include <cstddef>

#define DIM 2048
#define NTOK 8192
#define NEUMANN_ITERS 6

// Math (validated rounds 1-20):
//   omega = P Q^T, P=[U|V], Q=[sV|-sU], G = Q^T P  (16x16)
//   Y = (I - G/2)^{-1}(I + G/2)  via Neumann-Horner: Y <- B + 0.5*G*Y, B=I+G/2
//   out = x + c . W^T,  c[r][k] = 0.5*s * sum_j Z[k][j] b[r][j],  Z = I + Y,
//     b[j<8] = av[j], b[j>=8] = -au[j-8];  a = [x.U | x.V] = x.W
//
// Round 20 conclusion: 10 VALU-path variants all land 40-47us fused; the
// three-pipe sum (HBM 21 + LDS 10-20 + VALU 10-17 us/CU) can't overlap
// better. THIS round: both phases on MFMA (v_mfma_f32_16x16x16f16,
// classic layout: A row=l&15 k=(l>>4)*4+j; B col=l&15 same k; D col=l&15
// row=(l>>4)*4+reg per m89) -> VALU/LDS terms collapse, HBM-bound.
//   - Block 256thr/4 waves owns 16 rows; phase1 K-split 4 ways + LDS
//     reduce; c-fragment computed directly in phase-2 A layout.
//   - B-fragments gathered from the validated uvQ f16-pair layout
//     (phase1: 2x ds_read_b32; phase2: 1x ds_read_b128 + parity select).
//   - f32 MFMA accumulation (better than r11-r20's hfma2 chains).
//   - No min-waves clause; 256-thr block caps VGPR at 256 (no spill risk).
//   - cvt_pkrtz returns __fp16 ext_vector(2): bit_cast everywhere.

typedef _Float16 h4 __attribute__((ext_vector_type(4)));
typedef float f32x4 __attribute__((ext_vector_type(4)));

__device__ __forceinline__ unsigned pkh(float lo, float hi) {
  auto p = __builtin_amdgcn_cvt_pkrtz(lo, hi);   // v_cvt_pkrtz_f16_f32
  return __builtin_bit_cast(unsigned, p);
}

// ---------------------------------------------------------------------------
// 1) Gram: one block per entry e=(q,i,j); 256 threads reduce over d=2048.
// ---------------------------------------------------------------------------
__global__ __launch_bounds__(256) void rora_gram(
    const float* __restrict__ U, const float* __restrict__ V,
    float* __restrict__ prod) {
  const int e = blockIdx.x;            // 0..191
  const int q = e >> 6;                // 0: U^T U, 1: U^T V, 2: V^T V
  const int i = (e >> 3) & 7, j = e & 7;
  const float* A = (q == 2) ? V : U;
  const float* B = (q == 0) ? U : V;
  const int t = threadIdx.x;
  float acc = 0.f;
#pragma unroll
  for (int s = 0; s < 8; ++s) {
    const int d = s * 256 + t;
    acc = fmaf(A[d * 8 + i], B[d * 8 + j], acc);
  }
#pragma unroll
  for (int m = 1; m < 64; m <<= 1) acc += __shfl_xor(acc, m, 64);
  __shared__ float wsum[4];
  if ((t & 63) == 0) wsum[t >> 6] = acc;
  __syncthreads();
  if (t == 0) prod[e] = (wsum[0] + wsum[1]) + (wsum[2] + wsum[3]);
}

// ---------------------------------------------------------------------------
// 2) Fused MFMA kernel. uvQ[q][P].comp(m) = half2(W[2P][4q+m], W[2P+1][4q+m])
//    (validated layout). 256 thr = 4 waves; block owns 16 rows; grid 512.
// ---------------------------------------------------------------------------
__global__ __launch_bounds__(256) void rora_fused(
    const float* __restrict__ x, const float* __restrict__ U,
    const float* __restrict__ V, const float* __restrict__ gate,
    const float* __restrict__ prod, float* __restrict__ out) {
  __shared__ uint4 uvQ[4][DIM / 2];   // 64 KB
  __shared__ float prodS[192];
  __shared__ float Gs[16][17];
  __shared__ float Bm[16][17];
  __shared__ float Ya[16][17];
  __shared__ float Yb[16][17];
  __shared__ float Ared[4][64][4];    // per-wave phase-1 C partials
  __shared__ float As[16][17];        // reduced a[row][k]
  const int t = threadIdx.x;
  const int lane = t & 63, wv = t >> 6;

  // ---- stage U,V -> LDS as f16 d-pairs (4 pairs per thread) ----
  {
    const float4* U4 = (const float4*)U;
    const float4* V4 = (const float4*)V;
#pragma unroll
    for (int rep = 0; rep < 4; ++rep) {
      const int P = rep * 256 + t;    // d-pair (2P, 2P+1)
      const float4 a0 = U4[4 * P + 0], a1 = U4[4 * P + 1];
      const float4 a2 = U4[4 * P + 2], a3 = U4[4 * P + 3];
      const float4 b0 = V4[4 * P + 0], b1 = V4[4 * P + 1];
      const float4 b2 = V4[4 * P + 2], b3 = V4[4 * P + 3];
      uvQ[0][P] = make_uint4(pkh(a0.x, a2.x), pkh(a0.y, a2.y),
                             pkh(a0.z, a2.z), pkh(a0.w, a2.w));
      uvQ[1][P] = make_uint4(pkh(a1.x, a3.x), pkh(a1.y, a3.y),
                             pkh(a1.z, a3.z), pkh(a1.w, a3.w));
      uvQ[2][P] = make_uint4(pkh(b0.x, b2.x), pkh(b0.y, b2.y),
                             pkh(b0.z, b2.z), pkh(b0.w, b2.w));
      uvQ[3][P] = make_uint4(pkh(b1.x, b3.x), pkh(b1.y, b3.y),
                             pkh(b1.z, b3.z), pkh(b1.w, b3.w));
    }
  }

  // ---- 16x16 setup ----
  if (t < 192) prodS[t] = prod[t];
  __syncthreads();
  const float sg = 1.f / (1.f + expf(-gate[0]));
  {
    const int r = t >> 4, c = t & 15;
    float g;
    if (r < 8) g = (c < 8) ? sg * prodS[64 + c * 8 + r]              // (V^T U)
                           : sg * prodS[128 + r * 8 + (c - 8)];      // (V^T V)
    else       g = (c < 8) ? -sg * prodS[(r - 8) * 8 + c]            // -(U^T U)
                           : -sg * prodS[64 + (r - 8) * 8 + (c - 8)];
    const float b = ((r == c) ? 1.f : 0.f) + 0.5f * g;
    Gs[r][c] = g;
    Bm[r][c] = b;
    Ya[r][c] = b;
  }
  __syncthreads();
#pragma unroll
  for (int m = 0; m < NEUMANN_ITERS; ++m) {   // ends in Ya (last m odd)
    const int r = t >> 4, c = t & 15;
    const float (*Yp)[17] = (m & 1) ? Yb : Ya;
    float (*Yn)[17] = (m & 1) ? Ya : Yb;
    float acc = Bm[r][c];
#pragma unroll
    for (int j = 0; j < 16; ++j)
      acc = fmaf(0.5f * Gs[r][j], Yp[j][c], acc);
    Yn[r][c] = acc;
    __syncthreads();   // final barrier also orders uvQ staging
  }

  // ---- phase 1: a = x.W via MFMA; wave wv covers K-slice [wv*512, +512) ----
  const int row0 = blockIdx.x * 16;
  const int rA = lane & 15, g = lane >> 4;
  f32x4 acc = {0.f, 0.f, 0.f, 0.f};
  {
    const float* xrow = x + (size_t)(row0 + rA) * DIM;
    const int q1 = rA >> 2, c1 = rA & 3;   // B column k = rA
    const unsigned* uvW = (const unsigned*)&uvQ[q1][0];
#pragma unroll 4
    for (int step = 0; step < 32; ++step) {
      const int d0 = wv * 512 + step * 16 + g * 4;
      const float4 xv = *(const float4*)(xrow + d0);
      uint2 au = {pkh(xv.x, xv.y), pkh(xv.z, xv.w)};
      const h4 af = __builtin_bit_cast(h4, au);
      const int P0 = d0 >> 1;
      uint2 bu = {uvW[P0 * 4 + c1], uvW[(P0 + 1) * 4 + c1]};
      const h4 bf = __builtin_bit_cast(h4, bu);
      acc = __builtin_amdgcn_mfma_f32_16x16x16f16(af, bf, acc, 0, 0, 0);
    }
  }
  Ared[wv][lane][0] = acc[0];
  Ared[wv][lane][1] = acc[1];
  Ared[wv][lane][2] = acc[2];
  Ared[wv][lane][3] = acc[3];
  __syncthreads();
  {
    const int l = t & 63, j = t >> 6;
    const float s = (Ared[0][l][j] + Ared[1][l][j]) +
                    (Ared[2][l][j] + Ared[3][l][j]);
    As[(l >> 4) * 4 + j][l & 15] = s;   // a[row][k], D layout per m89
  }
  __syncthreads();

  // ---- c fragment (phase-2 A layout: lane holds c[r=lane&15][(g)*4+j]) ----
  h4 cf;
  {
    const float hs = 0.5f * sg;
    const int r = rA;
    float cj[4];
#pragma unroll
    for (int j = 0; j < 4; ++j) {
      const int k = g * 4 + j;
      float s = 0.f;
#pragma unroll
      for (int jj = 0; jj < 8; ++jj) {
        const float zA = Ya[k][jj] + ((k == jj) ? 1.f : 0.f);
        const float zB = Ya[k][8 + jj] + ((k == 8 + jj) ? 1.f : 0.f);
        s = fmaf(zA, As[r][8 + jj], s);    //  Z[k][j']   * av[j']
        s = fmaf(-zB, As[r][jj], s);       // -Z[k][8+j'] * au[j']
      }
      cj[j] = hs * s;
    }
    uint2 cu = {pkh(cj[0], cj[1]), pkh(cj[2], cj[3])};
    cf = __builtin_bit_cast(h4, cu);
  }

  // ---- phase 2: out = x + c.W^T via MFMA; wave wv does 32 n-tiles ----
  {
    const int par = rA & 1;
    for (int nt = wv * 32; nt < wv * 32 + 32; ++nt) {
      const int dcol0 = nt * 16;
      const uint4 wq = uvQ[g][(dcol0 + rA) >> 1];  // q = k>>2 = g
      const unsigned w01 = par ? ((wq.x >> 16) | (wq.y & 0xffff0000u))
                               : ((wq.x & 0xffffu) | (wq.y << 16));
      const unsigned w23 = par ? ((wq.z >> 16) | (wq.w & 0xffff0000u))
                               : ((wq.z & 0xffffu) | (wq.w << 16));
      uint2 bu = {w01, w23};
      const h4 bf = __builtin_bit_cast(h4, bu);
      f32x4 z4 = {0.f, 0.f, 0.f, 0.f};
      const f32x4 o = __builtin_amdgcn_mfma_f32_16x16x16f16(cf, bf, z4, 0, 0, 0);
      const float* xp = x + (size_t)(row0 + g * 4) * DIM + dcol0 + rA;
      float* op = out + (size_t)(row0 + g * 4) * DIM + dcol0 + rA;
#pragma unroll
      for (int j = 0; j < 4; ++j)
        op[(size_t)j * DIM] = xp[(size_t)j * DIM] + o[j];
    }
  }
}

extern "C" void kernel_launch(void* const* d_in, const int* in_sizes, int n_in,
                              void* d_out, int out_size, void* d_ws, size_t ws_size,
                              hipStream_t stream) {
  const float* x    = (const float*)d_in[0];
  const float* U    = (const float*)d_in[1];
  const float* V    = (const float*)d_in[2];
  const float* gate = (const float*)d_in[3];
  float* out = (float*)d_out;
  float* prodw = (float*)d_ws;   // 192 floats

  rora_gram<<<192, 256, 0, stream>>>(U, V, prodw);
  rora_fused<<<NTOK / 16, 256, 0, stream>>>(x, U, V, gate, prodw, out);
}